// Round 1
// baseline (2223.654 us; speedup 1.0000x reference)
//
#include <hip/hip_runtime.h>
#include <cstdint>
#include <cstddef>

// Problem constants (fixed by harness)
#define B_  32
#define S_  64
#define T_  64
#define E_  512
#define H_  1024   // = 2E
#define VT_ 32000

using short8  = __attribute__((ext_vector_type(8))) short;
using floatx4 = __attribute__((ext_vector_type(4))) float;
using us4     = __attribute__((ext_vector_type(4))) unsigned short;

__device__ __forceinline__ unsigned short f2bf(float f) {
  unsigned int u = __builtin_bit_cast(unsigned int, f);
  u = u + 0x7fffu + ((u >> 16) & 1u);     // RNE
  return (unsigned short)(u >> 16);
}
__device__ __forceinline__ float sigf(float x) { return 1.f / (1.f + __expf(-x)); }

// ---------------- enc = concat(enc_emb[src], pos_emb[pos])  [B*S][1024] f32
__global__ void build_enc(const int* __restrict__ ss, const int* __restrict__ pp,
                          const float* __restrict__ enc_emb, const float* __restrict__ pos_emb,
                          float* __restrict__ enc) {
  int row = blockIdx.x, tid = threadIdx.x;
  int tok = ss[row], pos = pp[row];
  float2 a = *(const float2*)&enc_emb[(size_t)tok * E_ + tid * 2];
  float2 p = *(const float2*)&pos_emb[(size_t)pos * E_ + tid * 2];
  *(float2*)&enc[(size_t)row * 1024 + tid * 2]       = a;
  *(float2*)&enc[(size_t)row * 1024 + 512 + tid * 2] = p;
}

// ---------------- encmean[b][d] = mean over s
__global__ void enc_mean(const float* __restrict__ enc, float* __restrict__ em) {
  int b = blockIdx.x, tid = threadIdx.x;
  float4 acc = {0, 0, 0, 0};
  for (int s = 0; s < S_; ++s) {
    float4 v = *(const float4*)&enc[((size_t)b * S_ + s) * 1024 + tid * 4];
    acc.x += v.x; acc.y += v.y; acc.z += v.z; acc.w += v.w;
  }
  const float inv = 1.f / 64.f;
  acc.x *= inv; acc.y *= inv; acc.z *= inv; acc.w *= inv;
  *(float4*)&em[(size_t)b * 1024 + tid * 4] = acc;
}

// ---------------- h0 = encmean @ W_h0^T + b_h0 ; c0 = h0 (wave-per-output dot)
__global__ __launch_bounds__(256) void h0_kernel(
    const float* __restrict__ em, const float* __restrict__ W_h0, const float* __restrict__ b_h0,
    float* __restrict__ hbuf, float* __restrict__ cbuf, unsigned short* __restrict__ xbuf) {
  int o = blockIdx.x * 4 + (threadIdx.x >> 6);
  int l = threadIdx.x & 63;
  int b = o >> 10, j = o & 1023;
  const float* wr = &W_h0[(size_t)j * 1024];
  const float* ev = &em[(size_t)b * 1024];
  float v = 0.f;
  #pragma unroll
  for (int i = 0; i < 16; ++i) v += wr[l + i * 64] * ev[l + i * 64];
  #pragma unroll
  for (int off = 32; off; off >>= 1) v += __shfl_down(v, off);
  if (l == 0) {
    v += b_h0[j];
    hbuf[b * 1024 + j] = v;
    cbuf[b * 1024 + j] = v;
    xbuf[b * 2048 + 1024 + j] = f2bf(v);
  }
}

// ---------------- words_bf[m = t*32+b][512] = bf16(dec_emb[target[b][t]])
__global__ void build_words(const int* __restrict__ ts, const float* __restrict__ dec_emb,
                            unsigned short* __restrict__ words_bf) {
  int bi = blockIdx.x;                 // = b*64 + t
  int b = bi >> 6, t = bi & 63;
  int tok = ts[bi];
  int m = t * 32 + b;
  int tid = threadIdx.x;
  float2 v = *(const float2*)&dec_emb[(size_t)tok * E_ + tid * 2];
  words_bf[(size_t)m * E_ + tid * 2]     = f2bf(v.x);
  words_bf[(size_t)m * E_ + tid * 2 + 1] = f2bf(v.y);
}

// ---------------- Wstep[r][0:1024]=W_ih[r][512:1536], [1024:2048]=W_hh[r][:]  (bf16)
__global__ void cast_wstep(const float* __restrict__ W_ih, const float* __restrict__ W_hh,
                           unsigned short* __restrict__ Wstep) {
  int r = blockIdx.x, c = threadIdx.x * 4;
  float4 a = *(const float4*)&W_ih[(size_t)r * 1536 + 512 + c];
  float4 h = *(const float4*)&W_hh[(size_t)r * 1024 + c];
  us4 va; va[0] = f2bf(a.x); va[1] = f2bf(a.y); va[2] = f2bf(a.z); va[3] = f2bf(a.w);
  us4 vh; vh[0] = f2bf(h.x); vh[1] = f2bf(h.y); vh[2] = f2bf(h.z); vh[3] = f2bf(h.w);
  *(us4*)&Wstep[(size_t)r * 2048 + c]        = va;
  *(us4*)&Wstep[(size_t)r * 2048 + 1024 + c] = vh;
}

// ---------------- generic MFMA GEMM: C[M][N] = A[M][K](bf16) @ B[N][K](f32->bf16)^T + biases
// tile 128x128, BK=32, 4 waves (2x2), each wave 64x64 (4x4 MFMA tiles)
// mode 0: C[m*ldc + n]   mode 1: C[((m&31)*64 + (m>>5))*ldc + n]
__global__ __launch_bounds__(256) void gemm_bf16(
    const unsigned short* __restrict__ A, int lda,
    const float* __restrict__ Bw, int ldb,
    float* __restrict__ C, int ldc,
    const float* __restrict__ bias1, const float* __restrict__ bias2,
    int K, int mode) {
  __shared__ unsigned short sA[128 * 32];
  __shared__ unsigned short sB[128 * 32];
  const int tid = threadIdx.x;
  const int n0 = blockIdx.x * 128, m0 = blockIdx.y * 128;
  const int w = tid >> 6, l = tid & 63;
  const int wm = w >> 1, wn = w & 1;
  const int l15 = l & 15, q = l >> 4;

  floatx4 acc[4][4];
  #pragma unroll
  for (int i = 0; i < 4; ++i)
    #pragma unroll
    for (int j = 0; j < 4; ++j) acc[i][j] = (floatx4){0.f, 0.f, 0.f, 0.f};

  for (int k0 = 0; k0 < K; k0 += 32) {
    __syncthreads();
    // stage A (bf16): 128 rows x 32 k = 8 KB, 2 passes of 16B/thread
    #pragma unroll
    for (int p = 0; p < 2; ++p) {
      int idx8 = p * 256 + tid;
      int row = idx8 >> 2, kc = (idx8 & 3) << 3;
      *(short8*)&sA[row * 32 + kc] =
          *(const short8*)&A[(size_t)(m0 + row) * lda + k0 + kc];
    }
    // stage B (f32 -> bf16): 4 passes of 4 floats/thread
    #pragma unroll
    for (int p = 0; p < 4; ++p) {
      int idx4 = p * 256 + tid;
      int row = idx4 >> 3, kc = (idx4 & 7) << 2;
      float4 f = *(const float4*)&Bw[(size_t)(n0 + row) * ldb + k0 + kc];
      us4 v; v[0] = f2bf(f.x); v[1] = f2bf(f.y); v[2] = f2bf(f.z); v[3] = f2bf(f.w);
      *(us4*)&sB[row * 32 + kc] = v;
    }
    __syncthreads();
    short8 af[4], bf8[4];
    #pragma unroll
    for (int mt = 0; mt < 4; ++mt)
      af[mt] = *(short8*)&sA[(wm * 64 + mt * 16 + l15) * 32 + q * 8];
    #pragma unroll
    for (int nt = 0; nt < 4; ++nt)
      bf8[nt] = *(short8*)&sB[(wn * 64 + nt * 16 + l15) * 32 + q * 8];
    #pragma unroll
    for (int mt = 0; mt < 4; ++mt)
      #pragma unroll
      for (int nt = 0; nt < 4; ++nt)
        acc[mt][nt] = __builtin_amdgcn_mfma_f32_16x16x32_bf16(af[mt], bf8[nt], acc[mt][nt], 0, 0, 0);
  }

  #pragma unroll
  for (int mt = 0; mt < 4; ++mt)
    #pragma unroll
    for (int nt = 0; nt < 4; ++nt)
      #pragma unroll
      for (int r = 0; r < 4; ++r) {
        int m = m0 + wm * 64 + mt * 16 + q * 4 + r;
        int n = n0 + wn * 64 + nt * 16 + l15;
        float v = acc[mt][nt][r];
        if (bias1) v += bias1[n];
        if (bias2) v += bias2[n];
        if (mode == 0) {
          C[(size_t)m * ldc + n] = v;
        } else {
          int b = m & 31, t = m >> 5;
          C[(size_t)(b * 64 + t) * ldc + n] = v;
        }
      }
}

// ---------------- per-step attention: energies, masked softmax, ctx -> xbuf[b][0:1024]
__global__ __launch_bounds__(256) void attn_ctx(
    const float* __restrict__ enc, const float* __restrict__ hbuf,
    const int* __restrict__ slen, unsigned short* __restrict__ xbuf) {
  __shared__ float hsh[1024];
  __shared__ float esh[64];
  __shared__ float ash[64];
  int b = blockIdx.x, tid = threadIdx.x;
  *(float4*)&hsh[tid * 4] = *(const float4*)&hbuf[(size_t)b * 1024 + tid * 4];
  __syncthreads();
  int w = tid >> 6, l = tid & 63;
  for (int si = 0; si < 16; ++si) {
    int s = w * 16 + si;
    const float* er = &enc[((size_t)b * S_ + s) * 1024];
    float v = 0.f;
    #pragma unroll
    for (int i = 0; i < 16; ++i) v += er[l + i * 64] * hsh[l + i * 64];
    #pragma unroll
    for (int off = 32; off; off >>= 1) v += __shfl_down(v, off);
    if (l == 0) esh[s] = v;
  }
  __syncthreads();
  if (tid < 64) {
    int len = slen[b];
    float e = (tid < len) ? esh[tid] : -1e30f;
    float m = e;
    #pragma unroll
    for (int off = 32; off; off >>= 1) m = fmaxf(m, __shfl_down(m, off));
    m = __shfl(m, 0);
    float p = (tid < len) ? __expf(e - m) : 0.f;
    float s = p;
    #pragma unroll
    for (int off = 32; off; off >>= 1) s += __shfl_down(s, off);
    s = __shfl(s, 0);
    ash[tid] = p / s;
  }
  __syncthreads();
  float4 acc = {0, 0, 0, 0};
  const float* eb = &enc[(size_t)b * S_ * 1024 + tid * 4];
  for (int s = 0; s < S_; ++s) {
    float a = ash[s];
    float4 ev = *(const float4*)&eb[(size_t)s * 1024];
    acc.x += a * ev.x; acc.y += a * ev.y; acc.z += a * ev.z; acc.w += a * ev.w;
  }
  int d0 = tid * 4;
  us4 v; v[0] = f2bf(acc.x); v[1] = f2bf(acc.y); v[2] = f2bf(acc.z); v[3] = f2bf(acc.w);
  *(us4*)&xbuf[(size_t)b * 2048 + d0] = v;
}

// ---------------- per-step gates + LSTM update
// grid 256 blocks; block owns 4 units (16 gate rows), 4 waves split K=2048 into 512-chunks
__global__ __launch_bounds__(256) void step_gates(
    const unsigned short* __restrict__ xbuf,   // [32][2048] bf16 (ctx|h)
    const unsigned short* __restrict__ Wstep,  // [4096][2048] bf16
    const float* __restrict__ gw,              // [2048][4096] f32 (word part + biases)
    float* __restrict__ hbuf, float* __restrict__ cbuf,
    unsigned short* __restrict__ hs,           // [2048][1024] bf16
    int t) {
  __shared__ float red[4 * 512];
  const int tid = threadIdx.x;
  const int w = tid >> 6, l = tid & 63;
  const int l15 = l & 15, q = l >> 4;
  const int u0 = blockIdx.x * 4;
  const int rn = (l15 >> 2) * 1024 + u0 + (l15 & 3);  // gate row for n=l15
  floatx4 acc0 = (floatx4){0.f, 0.f, 0.f, 0.f};
  floatx4 acc1 = (floatx4){0.f, 0.f, 0.f, 0.f};
  const int kbase = w * 512;
  #pragma unroll 4
  for (int ks = 0; ks < 16; ++ks) {
    int k0 = kbase + ks * 32 + q * 8;
    short8 b8 = *(const short8*)&Wstep[(size_t)rn * 2048 + k0];
    short8 a0 = *(const short8*)&xbuf[(size_t)l15 * 2048 + k0];
    short8 a1 = *(const short8*)&xbuf[(size_t)(16 + l15) * 2048 + k0];
    acc0 = __builtin_amdgcn_mfma_f32_16x16x32_bf16(a0, b8, acc0, 0, 0, 0);
    acc1 = __builtin_amdgcn_mfma_f32_16x16x32_bf16(a1, b8, acc1, 0, 0, 0);
  }
  #pragma unroll
  for (int r = 0; r < 4; ++r) {
    red[w * 512 + (q * 4 + r) * 16 + l15]        = acc0[r];
    red[w * 512 + (16 + q * 4 + r) * 16 + l15]   = acc1[r];
  }
  __syncthreads();
  if (tid < 128) {
    int b = tid >> 2, ui = tid & 3;
    float g4[4];
    #pragma unroll
    for (int g = 0; g < 4; ++g) {
      int n = g * 4 + ui;
      float s = red[b * 16 + n] + red[512 + b * 16 + n] +
                red[1024 + b * 16 + n] + red[1536 + b * 16 + n];
      s += gw[(size_t)(t * 32 + b) * 4096 + g * 1024 + u0 + ui];
      g4[g] = s;
    }
    int u = u0 + ui;
    float c_old = cbuf[b * 1024 + u];
    float fi = sigf(g4[0]);
    float ff = sigf(g4[1]);
    float gg = tanhf(g4[2]);
    float fo = sigf(g4[3]);
    float cn = ff * c_old + fi * gg;
    float hn = fo * tanhf(cn);
    cbuf[b * 1024 + u] = cn;
    hbuf[b * 1024 + u] = hn;
    unsigned short hb = f2bf(hn);
    const_cast<unsigned short*>(xbuf)[b * 2048 + 1024 + u] = hb;
    hs[(size_t)(t * 32 + b) * 1024 + u] = hb;
  }
}

extern "C" void kernel_launch(void* const* d_in, const int* in_sizes, int n_in,
                              void* d_out, int out_size, void* d_ws, size_t ws_size,
                              hipStream_t stream) {
  const int*   ts     = (const int*)d_in[0];    // target_sentences [B,T]
  const int*   slen   = (const int*)d_in[2];    // source_lengths [B]
  const int*   ss     = (const int*)d_in[3];    // source_sentences [B,S]
  const int*   pp     = (const int*)d_in[4];    // positions [B,S]
  const float* enc_emb = (const float*)d_in[8];
  const float* pos_emb = (const float*)d_in[9];
  const float* dec_emb = (const float*)d_in[10];
  const float* W_h0   = (const float*)d_in[11];
  const float* b_h0   = (const float*)d_in[12];
  const float* W_ih   = (const float*)d_in[13];
  const float* W_hh   = (const float*)d_in[14];
  const float* b_ih   = (const float*)d_in[15];
  const float* b_hh   = (const float*)d_in[16];
  const float* W_out  = (const float*)d_in[17];
  const float* b_out  = (const float*)d_in[18];
  float* out = (float*)d_out;

  // workspace carve-up
  char* base = (char*)d_ws;
  size_t off = 0;
  auto carve = [&](size_t bytes) { void* p = base + off; off += (bytes + 255) & ~(size_t)255; return p; };
  float*          enc      = (float*)carve((size_t)B_ * S_ * 1024 * 4);      // 8.39 MB
  float*          em       = (float*)carve((size_t)B_ * 1024 * 4);
  float*          hbuf     = (float*)carve((size_t)B_ * 1024 * 4);
  float*          cbuf     = (float*)carve((size_t)B_ * 1024 * 4);
  unsigned short* xbuf     = (unsigned short*)carve((size_t)B_ * 2048 * 2);
  unsigned short* words_bf = (unsigned short*)carve((size_t)2048 * E_ * 2);  // 2.10 MB
  unsigned short* Wstep    = (unsigned short*)carve((size_t)4096 * 2048 * 2);// 16.8 MB
  float*          gw       = (float*)carve((size_t)2048 * 4096 * 4);         // 33.6 MB
  unsigned short* hs       = (unsigned short*)carve((size_t)2048 * 1024 * 2);// 4.19 MB

  // ---- prep (parallel, order enforced by stream)
  build_enc  <<<B_ * S_, 256, 0, stream>>>(ss, pp, enc_emb, pos_emb, enc);
  enc_mean   <<<B_,      256, 0, stream>>>(enc, em);
  h0_kernel  <<<(B_ * H_) / 4, 256, 0, stream>>>(em, W_h0, b_h0, hbuf, cbuf, xbuf);
  build_words<<<B_ * T_, 256, 0, stream>>>(ts, dec_emb, words_bf);
  cast_wstep <<<4096,    256, 0, stream>>>(W_ih, W_hh, Wstep);
  // gw = words @ W_ih[:, :512]^T + b_ih + b_hh    (M=2048, N=4096, K=512)
  gemm_bf16<<<dim3(4096 / 128, 2048 / 128), 256, 0, stream>>>(
      words_bf, E_, W_ih, 1536, gw, 4096, b_ih, b_hh, E_, 0);

  // ---- recurrence
  for (int t = 0; t < T_; ++t) {
    attn_ctx  <<<B_,  256, 0, stream>>>(enc, hbuf, slen, xbuf);
    step_gates<<<256, 256, 0, stream>>>(xbuf, Wstep, gw, hbuf, cbuf, hs, t);
  }

  // ---- out = hs @ W_out^T + b_out  (M=2048, N=32000, K=1024), remapped to [B,T,V]
  gemm_bf16<<<dim3(VT_ / 128, 2048 / 128), 256, 0, stream>>>(
      hs, H_, W_out, H_, out, VT_, b_out, nullptr, H_, 1);
}